// Round 11
// baseline (1165.776 us; speedup 1.0000x reference)
//
#include <hip/hip_runtime.h>

typedef __attribute__((ext_vector_type(8))) __bf16 bf16x8;
typedef __attribute__((ext_vector_type(4))) float f32x4;

#define GLOAD_LDS16(g, l)                                                     \
  __builtin_amdgcn_global_load_lds(                                           \
      (const __attribute__((address_space(1))) void*)(g),                     \
      (__attribute__((address_space(3))) void*)(l), 16, 0, 0)

#define BAR() __builtin_amdgcn_s_barrier()
#define SB0() __builtin_amdgcn_sched_barrier(0)
#define LGKM(n)                                                               \
  do {                                                                        \
    asm volatile("s_waitcnt lgkmcnt(" #n ")" ::: "memory");                   \
    SB0();                                                                    \
  } while (0)
#define VMCNT0() asm volatile("s_waitcnt vmcnt(0)" ::: "memory")
#define PRIO1() __builtin_amdgcn_s_setprio(1)
#define PRIO0() __builtin_amdgcn_s_setprio(0)
#define MFMA_BF16 __builtin_amdgcn_mfma_f32_16x16x32_bf16

__device__ __forceinline__ unsigned short f32_to_bf16(float f) {
  unsigned int u = __builtin_bit_cast(unsigned int, f);
  u += 0x7FFFu + ((u >> 16) & 1u);
  return (unsigned short)(u >> 16);
}

// ---------------- f32 -> bf16 conversion ----------------------------------
__global__ void conv_f32_bf16(const float* __restrict__ in,
                              unsigned short* __restrict__ out, int n4) {
  int stride = gridDim.x * blockDim.x;
  for (int i = blockIdx.x * blockDim.x + threadIdx.x; i < n4; i += stride) {
    float4 v = reinterpret_cast<const float4*>(in)[i];
    ushort4 o;
    o.x = f32_to_bf16(v.x);
    o.y = f32_to_bf16(v.y);
    o.z = f32_to_bf16(v.z);
    o.w = f32_to_bf16(v.w);
    reinterpret_cast<ushort4*>(out)[i] = o;
  }
}

// ---------------- FWHT rows of 8192, * 1/sqrt(8192), bf16 out --------------
__global__ void fwht_rows_bf16(const float* __restrict__ in,
                               unsigned short* __restrict__ out) {
  __shared__ float s[8192];
  const int tid = threadIdx.x;  // 256 threads
  const float* row = in + (size_t)blockIdx.x * 8192;
#pragma unroll
  for (int i = 0; i < 8; ++i)
    reinterpret_cast<float4*>(s)[tid + i * 256] =
        reinterpret_cast<const float4*>(row)[tid + i * 256];
  for (int h = 1; h < 8192; h <<= 1) {
    __syncthreads();
#pragma unroll
    for (int it = 0; it < 16; ++it) {
      int i = tid + it * 256;
      int j = ((i & ~(h - 1)) << 1) | (i & (h - 1));
      float a = s[j], b = s[j + h];
      s[j] = a + b;
      s[j + h] = a - b;
    }
  }
  __syncthreads();
  const float scale = 0.011048543456039806f;  // 1/sqrt(8192)
  unsigned short* orow = out + (size_t)blockIdx.x * 8192;
#pragma unroll
  for (int i = 0; i < 8; ++i) {
    float4 v = reinterpret_cast<const float4*>(s)[tid + i * 256];
    ushort4 o;
    o.x = f32_to_bf16(v.x * scale);
    o.y = f32_to_bf16(v.y * scale);
    o.z = f32_to_bf16(v.z * scale);
    o.w = f32_to_bf16(v.w * scale);
    reinterpret_cast<ushort4*>(orow)[tid + i * 256] = o;
  }
}

#define RD_A(arr, mi, bi)                                                     \
  arr[0] = *(const bf16x8*)(Lb + ((bi)*32768 + (mi)*2048) + rA0);             \
  arr[1] = *(const bf16x8*)(Lb + ((bi)*32768 + (mi)*2048) + rA1);
#define RD_B(arr, ni, bi)                                                     \
  arr[0] = *(const bf16x8*)(Lb + ((bi)*32768 + (ni)*2048) + rB0);             \
  arr[1] = *(const bf16x8*)(Lb + ((bi)*32768 + (ni)*2048) + rB1);

// ======================= GEMM2: C(f32) = A · Bt^T ==========================
// tile 256x256, BK=64, 8 waves (2M x 4N), per-wave 128x64.
// Rotated schedule: last MFMA group (m67 x n0-3) of tile t executes at the
// head of tile t+1, overlapping t+1's first read burst. Operands (ra67, rb)
// carried in registers across the barrier; read order arranged so they are
// not overwritten before use. 1 barrier + 1 vmcnt(0) per K-tile.
#define G2_TILE(bi, tt)                                                       \
  {                                                                           \
    if ((tt) + 1 < NT) {                                                      \
      unsigned short* dA = L + (((bi) ^ 1) * 16384) + wid * 512;              \
      unsigned short* dB = L + 32768 + (((bi) ^ 1) * 16384) + wid * 512;      \
      _Pragma("unroll") for (int i = 0; i < 4; ++i) {                         \
        GLOAD_LDS16(pA + i * s64, dA + i * 4096);                             \
        GLOAD_LDS16(pB + i * s64, dB + i * 4096);                             \
      }                                                                       \
    }                                                                         \
    SB0();                                                                    \
    /* G0: A m0-3 (8 reads) -- does not touch M4_prev operands */             \
    RD_A(ra_lo[0], 0, bi) RD_A(ra_lo[1], 1, bi)                               \
    RD_A(ra_mi[0], 2, bi) RD_A(ra_mi[1], 3, bi)                               \
    SB0();                                                                    \
    if ((tt) > 0) { /* deferred M4 of tile tt-1: m67 x n0-3 */                \
      PRIO1();                                                                \
      _Pragma("unroll") for (int ks = 0; ks < 2; ++ks)                        \
          _Pragma("unroll") for (int j = 0; j < 2; ++j)                       \
              _Pragma("unroll") for (int n = 0; n < 4; ++n) acc[6 + j][n] =   \
                  MFMA_BF16(ra_67[j][ks], rb[n][ks], acc[6 + j][n], 0, 0, 0); \
      PRIO0();                                                                \
    }                                                                         \
    SB0();                                                                    \
    /* G1+G2: B n0-3 (8 reads) */                                             \
    RD_B(rb[0], 0, bi) RD_B(rb[1], 1, bi)                                     \
    RD_B(rb[2], 2, bi) RD_B(rb[3], 3, bi)                                     \
    SB0();                                                                    \
    LGKM(4); /* G0 + B n01 done; B n23 outstanding */                         \
    PRIO1();                                                                  \
    _Pragma("unroll") for (int ks = 0; ks < 2; ++ks)                          \
        _Pragma("unroll") for (int j = 0; j < 2; ++j)                         \
            _Pragma("unroll") for (int n = 0; n < 2; ++n) {                   \
      acc[j][n] = MFMA_BF16(ra_lo[j][ks], rb[n][ks], acc[j][n], 0, 0, 0);     \
      acc[2 + j][n] = MFMA_BF16(ra_mi[j][ks], rb[n][ks], acc[2 + j][n], 0,    \
                                0, 0);                                        \
    }                                                                         \
    PRIO0();                                                                  \
    SB0();                                                                    \
    /* G3: A m45 */                                                           \
    RD_A(ra_45[0], 4, bi) RD_A(ra_45[1], 5, bi)                               \
    SB0();                                                                    \
    LGKM(4); /* B n23 done; G3 outstanding */                                 \
    PRIO1();                                                                  \
    _Pragma("unroll") for (int ks = 0; ks < 2; ++ks)                          \
        _Pragma("unroll") for (int j = 0; j < 2; ++j)                         \
            _Pragma("unroll") for (int n = 2; n < 4; ++n) {                   \
      acc[j][n] = MFMA_BF16(ra_lo[j][ks], rb[n][ks], acc[j][n], 0, 0, 0);     \
      acc[2 + j][n] = MFMA_BF16(ra_mi[j][ks], rb[n][ks], acc[2 + j][n], 0,    \
                                0, 0);                                        \
    }                                                                         \
    PRIO0();                                                                  \
    SB0();                                                                    \
    /* G4: A m67 (operands for deferred M4) */                                \
    RD_A(ra_67[0], 6, bi) RD_A(ra_67[1], 7, bi)                               \
    SB0();                                                                    \
    LGKM(4); /* G3 done; G4 outstanding */                                    \
    PRIO1();                                                                  \
    _Pragma("unroll") for (int ks = 0; ks < 2; ++ks)                          \
        _Pragma("unroll") for (int j = 0; j < 2; ++j)                         \
            _Pragma("unroll") for (int n = 0; n < 4; ++n) acc[4 + j][n] =     \
                MFMA_BF16(ra_45[j][ks], rb[n][ks], acc[4 + j][n], 0, 0, 0);   \
    PRIO0();                                                                  \
    LGKM(0); /* G4 landed (used next iter) */                                 \
    VMCNT0();                                                                 \
    BAR();                                                                    \
    pA += 128;                                                                \
    pB += 128;                                                                \
  }

__launch_bounds__(512, 2)
__global__ void gemm2_rot(const unsigned short* __restrict__ A,
                          const unsigned short* __restrict__ Bt,
                          float* __restrict__ C, int M, int N, int K) {
  __shared__ __align__(16) unsigned short L[65536];  // A:[0,64KB) B:[64,128KB)
  const int tid = threadIdx.x, lane = tid & 63, wid = tid >> 6;
  const int wr = wid >> 2, wc = wid & 3;
  const int nbx = N >> 8;
  const int cpx = (int)gridDim.x >> 3;
  const int swz = ((int)blockIdx.x & 7) * cpx + ((int)blockIdx.x >> 3);
  const int bm = (swz / nbx) << 8, bn = (swz % nbx) << 8;
  const int NT = K >> 6;

  const int lp0 = (lane & 15) * 128 + (((lane >> 4) << 4) ^ ((lane & 7) << 4));
  const int lp1 =
      (lane & 15) * 128 + ((64 | ((lane >> 4) << 4)) ^ ((lane & 7) << 4));
  const int rA0 = wr * 16384 + lp0, rA1 = wr * 16384 + lp1;
  const int rB0 = 65536 + wc * 8192 + lp0, rB1 = 65536 + wc * 8192 + lp1;

  const int swzc = ((lane & 7) ^ (lane >> 3)) << 4;
  const char* pA = (const char*)A +
                   ((size_t)(bm + (wid << 3) + (lane >> 3)) * K) * 2 + swzc;
  const char* pB = (const char*)Bt +
                   ((size_t)(bn + (wid << 3) + (lane >> 3)) * K) * 2 + swzc;
  const size_t s64 = (size_t)K * 128;
  const char* Lb = (const char*)L;

  {  // prologue: stage tile 0 into buf0
    unsigned short* dA = L + wid * 512;
    unsigned short* dB = L + 32768 + wid * 512;
#pragma unroll
    for (int i = 0; i < 4; ++i) {
      GLOAD_LDS16(pA + i * s64, dA + i * 4096);
      GLOAD_LDS16(pB + i * s64, dB + i * 4096);
    }
  }
  pA += 128;
  pB += 128;

  f32x4 acc[8][4];
#pragma unroll
  for (int m = 0; m < 8; ++m)
#pragma unroll
    for (int n = 0; n < 4; ++n) acc[m][n] = (f32x4)0.0f;
  bf16x8 ra_lo[2][2], ra_mi[2][2], ra_45[2][2], ra_67[2][2], rb[4][2];

  VMCNT0();
  BAR();

  for (int t = 0; t < NT; t += 2) {
    G2_TILE(0, t)
    G2_TILE(1, t + 1)
  }
  // flush deferred M4 of last tile
  PRIO1();
#pragma unroll
  for (int ks = 0; ks < 2; ++ks)
#pragma unroll
    for (int j = 0; j < 2; ++j)
#pragma unroll
      for (int n = 0; n < 4; ++n)
        acc[6 + j][n] = MFMA_BF16(ra_67[j][ks], rb[n][ks], acc[6 + j][n], 0,
                                  0, 0);
  PRIO0();

  const int er = (lane >> 4) << 2;
  const int ec = lane & 15;
#pragma unroll
  for (int mi = 0; mi < 8; ++mi)
#pragma unroll
    for (int n = 0; n < 4; ++n)
#pragma unroll
      for (int r = 0; r < 4; ++r) {
        size_t row = (size_t)(bm + wr * 128 + mi * 16 + er + r);
        size_t col = (size_t)(bn + wc * 64 + n * 16 + ec);
        C[row * N + col] = acc[mi][n][r];
      }
}

// ======================= GEMM1: dual-B + silu fuse =========================
// tile 256x128, BK=64, 8 waves (4M x 2N), per-wave 64x64, dual accum.
// LDS (ushorts): A [0,32768), B1 [32768,49152), B3 [49152,65536).
// Rotated: deferred group = L n23 (ra x rb3hi); runs at next tile head over
// the B1 read burst. ra/rb3hi carried across the barrier.
#define RD_A1(arr, mi, bi)                                                    \
  arr[0] = *(const bf16x8*)(Lb + ((bi)*32768 + (mi)*2048) + rA0);             \
  arr[1] = *(const bf16x8*)(Lb + ((bi)*32768 + (mi)*2048) + rA1);
#define RD_B1(arr, ni, bi)                                                    \
  arr[0] = *(const bf16x8*)(Lb + (65536 + (bi)*16384 + (ni)*2048) + rBp0);    \
  arr[1] = *(const bf16x8*)(Lb + (65536 + (bi)*16384 + (ni)*2048) + rBp1);
#define RD_B3(arr, ni, bi)                                                    \
  arr[0] = *(const bf16x8*)(Lb + (98304 + (bi)*16384 + (ni)*2048) + rBp0);    \
  arr[1] = *(const bf16x8*)(Lb + (98304 + (bi)*16384 + (ni)*2048) + rBp1);

#define G1_TILE(bi, tt)                                                       \
  {                                                                           \
    if ((tt) + 1 < NT) {                                                      \
      unsigned short* dA = L + (((bi) ^ 1) * 16384) + wid * 512;              \
      unsigned short* dB1 = L + 32768 + (((bi) ^ 1) * 8192) + wid * 512;      \
      unsigned short* dB3 = L + 49152 + (((bi) ^ 1) * 8192) + wid * 512;      \
      _Pragma("unroll") for (int i = 0; i < 4; ++i)                           \
          GLOAD_LDS16(pA + i * s64, dA + i * 4096);                           \
      _Pragma("unroll") for (int i = 0; i < 2; ++i) {                         \
        GLOAD_LDS16(pB1 + i * s64, dB1 + i * 4096);                           \
        GLOAD_LDS16(pB3 + i * s64, dB3 + i * 4096);                           \
      }                                                                       \
    }                                                                         \
    SB0();                                                                    \
    /* G0: B1 n0-3 (8 reads) -- no collision with deferred operands */        \
    RD_B1(rb1[0], 0, bi) RD_B1(rb1[1], 1, bi)                                 \
    RD_B1(rb1[2], 2, bi) RD_B1(rb1[3], 3, bi)                                 \
    SB0();                                                                    \
    if ((tt) > 0) { /* deferred: L n23 of tile tt-1 (ra_old x rb3hi_old) */   \
      PRIO1();                                                                \
      _Pragma("unroll") for (int ks = 0; ks < 2; ++ks)                        \
          _Pragma("unroll") for (int m = 0; m < 4; ++m)                       \
              _Pragma("unroll") for (int n = 0; n < 2; ++n)                   \
                  accL[m][2 + n] = MFMA_BF16(ra[m][ks], rb3hi[n][ks],         \
                                             accL[m][2 + n], 0, 0, 0);        \
      PRIO0();                                                                \
    }                                                                         \
    SB0();                                                                    \
    /* G1: A m0-3 (8 reads) ; G2: B3 n23 (4) */                               \
    RD_A1(ra[0], 0, bi) RD_A1(ra[1], 1, bi)                                   \
    RD_A1(ra[2], 2, bi) RD_A1(ra[3], 3, bi)                                   \
    SB0();                                                                    \
    RD_B3(rb3hi[0], 2, bi) RD_B3(rb3hi[1], 3, bi)                             \
    SB0();                                                                    \
    LGKM(4); /* G0+G1 done; G2 outstanding */                                 \
    PRIO1();                                                                  \
    _Pragma("unroll") for (int ks = 0; ks < 2; ++ks)                          \
        _Pragma("unroll") for (int m = 0; m < 4; ++m)                         \
            _Pragma("unroll") for (int n = 0; n < 4; ++n) accG[m][n] =        \
                MFMA_BF16(ra[m][ks], rb1[n][ks], accG[m][n], 0, 0, 0);        \
    PRIO0();                                                                  \
    SB0();                                                                    \
    /* G3: B3 n01 (4) */                                                      \
    RD_B3(rb3lo[0], 0, bi) RD_B3(rb3lo[1], 1, bi)                             \
    SB0();                                                                    \
    LGKM(0); /* all reads landed */                                           \
    PRIO1();                                                                  \
    _Pragma("unroll") for (int ks = 0; ks < 2; ++ks)                          \
        _Pragma("unroll") for (int m = 0; m < 4; ++m)                         \
            _Pragma("unroll") for (int n = 0; n < 2; ++n) accL[m][n] =        \
                MFMA_BF16(ra[m][ks], rb3lo[n][ks], accL[m][n], 0, 0, 0);      \
    PRIO0();                                                                  \
    VMCNT0();                                                                 \
    BAR();                                                                    \
    pA += 128;                                                                \
    pB1 += 128;                                                               \
    pB3 += 128;                                                               \
  }

__launch_bounds__(512, 2)
__global__ void gemm1_rot(const unsigned short* __restrict__ A,
                          const unsigned short* __restrict__ B1p,
                          const unsigned short* __restrict__ B3p,
                          unsigned short* __restrict__ Hout, int M, int N,
                          int K) {
  __shared__ __align__(16) unsigned short L[65536];
  const int tid = threadIdx.x, lane = tid & 63, wid = tid >> 6;
  const int wr = wid >> 1, wc = wid & 1;
  const int nby = M >> 8;  // 32
  const int cpx = (int)gridDim.x >> 3;
  const int swz = ((int)blockIdx.x & 7) * cpx + ((int)blockIdx.x >> 3);
  const int bm = (swz % nby) << 8;
  const int bn = (swz / nby) << 7;
  const int NT = K >> 6;

  const int lp0 = (lane & 15) * 128 + (((lane >> 4) << 4) ^ ((lane & 7) << 4));
  const int lp1 =
      (lane & 15) * 128 + ((64 | ((lane >> 4) << 4)) ^ ((lane & 7) << 4));
  const int rA0 = wr * 8192 + lp0, rA1 = wr * 8192 + lp1;
  const int rBp0 = wc * 8192 + lp0, rBp1 = wc * 8192 + lp1;

  const int swzc = ((lane & 7) ^ (lane >> 3)) << 4;
  const char* pA = (const char*)A +
                   ((size_t)(bm + (wid << 3) + (lane >> 3)) * K) * 2 + swzc;
  const char* pB1 = (const char*)B1p +
                    ((size_t)(bn + (wid << 3) + (lane >> 3)) * K) * 2 + swzc;
  const char* pB3 = (const char*)B3p +
                    ((size_t)(bn + (wid << 3) + (lane >> 3)) * K) * 2 + swzc;
  const size_t s64 = (size_t)K * 128;
  const char* Lb = (const char*)L;

  {  // prologue
    unsigned short* dA = L + wid * 512;
    unsigned short* dB1 = L + 32768 + wid * 512;
    unsigned short* dB3 = L + 49152 + wid * 512;
#pragma unroll
    for (int i = 0; i < 4; ++i) GLOAD_LDS16(pA + i * s64, dA + i * 4096);
#pragma unroll
    for (int i = 0; i < 2; ++i) {
      GLOAD_LDS16(pB1 + i * s64, dB1 + i * 4096);
      GLOAD_LDS16(pB3 + i * s64, dB3 + i * 4096);
    }
  }
  pA += 128;
  pB1 += 128;
  pB3 += 128;

  f32x4 accG[4][4], accL[4][4];
#pragma unroll
  for (int m = 0; m < 4; ++m)
#pragma unroll
    for (int n = 0; n < 4; ++n) {
      accG[m][n] = (f32x4)0.0f;
      accL[m][n] = (f32x4)0.0f;
    }
  bf16x8 ra[4][2], rb1[4][2], rb3hi[2][2], rb3lo[2][2];

  VMCNT0();
  BAR();

  for (int t = 0; t < NT; t += 2) {
    G1_TILE(0, t)
    G1_TILE(1, t + 1)
  }
  // flush deferred L n23 of last tile
  PRIO1();
#pragma unroll
  for (int ks = 0; ks < 2; ++ks)
#pragma unroll
    for (int m = 0; m < 4; ++m)
#pragma unroll
      for (int n = 0; n < 2; ++n)
        accL[m][2 + n] =
            MFMA_BF16(ra[m][ks], rb3hi[n][ks], accL[m][2 + n], 0, 0, 0);
  PRIO0();

  const int er = (lane >> 4) << 2;
  const int ec = lane & 15;
#pragma unroll
  for (int m = 0; m < 4; ++m)
#pragma unroll
    for (int n = 0; n < 4; ++n)
#pragma unroll
      for (int r = 0; r < 4; ++r) {
        float g = accG[m][n][r];
        float li = accL[m][n][r];
        float h = (g / (1.0f + __expf(-g))) * li;
        size_t row = (size_t)(bm + wr * 64 + m * 16 + er + r);
        size_t col = (size_t)(bn + wc * 64 + n * 16 + ec);
        Hout[row * N + col] = f32_to_bf16(h);
      }
}

extern "C" void kernel_launch(void* const* d_in, const int* in_sizes, int n_in,
                              void* d_out, int out_size, void* d_ws,
                              size_t ws_size, hipStream_t stream) {
  const float* x = (const float*)d_in[0];   // (4,2048,2048)
  const float* W1 = (const float*)d_in[1];  // (8192,2048)
  const float* W2 = (const float*)d_in[2];  // (2048,8192)
  const float* W3 = (const float*)d_in[3];  // (8192,2048)
  float* out = (float*)d_out;

  const int M = 8192, D = 2048, H = 8192;
  const size_t NE = (size_t)16777216;

  unsigned short* xb = (unsigned short*)d_ws;
  unsigned short* w1b = xb + NE;
  unsigned short* w3b = w1b + NE;
  unsigned short* w2f = w3b + NE;
  unsigned short* hid = w2f + NE;  // M x H bf16

  conv_f32_bf16<<<2048, 256, 0, stream>>>(x, xb, (int)(NE / 4));
  conv_f32_bf16<<<2048, 256, 0, stream>>>(W1, w1b, (int)(NE / 4));
  conv_f32_bf16<<<2048, 256, 0, stream>>>(W3, w3b, (int)(NE / 4));
  fwht_rows_bf16<<<2048, 256, 0, stream>>>(W2, w2f);

  gemm1_rot<<<(M / 256) * (H / 128), 512, 0, stream>>>(xb, w1b, w3b, hid, M,
                                                       H, D);
  gemm2_rot<<<(M / 256) * (D / 256), 512, 0, stream>>>(hid, w2f, out, M, D,
                                                       H);
}

// Round 12
// 809.208 us; speedup vs baseline: 1.4406x; 1.4406x over previous
//
#include <hip/hip_runtime.h>

typedef __attribute__((ext_vector_type(8))) __bf16 bf16x8;
typedef __attribute__((ext_vector_type(4))) float f32x4;

#define GLOAD_LDS16(g, l)                                                     \
  __builtin_amdgcn_global_load_lds(                                           \
      (const __attribute__((address_space(1))) void*)(g),                     \
      (__attribute__((address_space(3))) void*)(l), 16, 0, 0)

#define BAR() __builtin_amdgcn_s_barrier()
#define SB0() __builtin_amdgcn_sched_barrier(0)
#define LGKM(n)                                                               \
  do {                                                                        \
    asm volatile("s_waitcnt lgkmcnt(" #n ")" ::: "memory");                   \
    SB0();                                                                    \
  } while (0)
#define VMCNT0() asm volatile("s_waitcnt vmcnt(0)" ::: "memory")
#define PRIO1() __builtin_amdgcn_s_setprio(1)
#define PRIO0() __builtin_amdgcn_s_setprio(0)
#define MFMA_BF16 __builtin_amdgcn_mfma_f32_16x16x32_bf16

__device__ __forceinline__ unsigned short f32_to_bf16(float f) {
  unsigned int u = __builtin_bit_cast(unsigned int, f);
  u += 0x7FFFu + ((u >> 16) & 1u);
  return (unsigned short)(u >> 16);
}

// ---------- merged f32 -> bf16 conversion for x, W1, W3 (one launch) -------
__global__ void conv3_f32_bf16(const float* __restrict__ s0,
                               unsigned short* __restrict__ d0,
                               const float* __restrict__ s1,
                               unsigned short* __restrict__ d1,
                               const float* __restrict__ s2,
                               unsigned short* __restrict__ d2, int n4) {
  const int seg = blockIdx.x >> 10;            // 1024 blocks per segment
  const int b = blockIdx.x & 1023;
  const float* in = (seg == 0) ? s0 : (seg == 1) ? s1 : s2;
  unsigned short* out = (seg == 0) ? d0 : (seg == 1) ? d1 : d2;
  const int stride = 1024 * blockDim.x;
  for (int i = b * blockDim.x + threadIdx.x; i < n4; i += stride) {
    float4 v = reinterpret_cast<const float4*>(in)[i];
    ushort4 o;
    o.x = f32_to_bf16(v.x);
    o.y = f32_to_bf16(v.y);
    o.z = f32_to_bf16(v.z);
    o.w = f32_to_bf16(v.w);
    reinterpret_cast<ushort4*>(out)[i] = o;
  }
}

// ---------------- FWHT rows of 8192, * 1/sqrt(8192), bf16 out --------------
__global__ void fwht_rows_bf16(const float* __restrict__ in,
                               unsigned short* __restrict__ out) {
  __shared__ float s[8192];
  const int tid = threadIdx.x;  // 256 threads
  const float* row = in + (size_t)blockIdx.x * 8192;
#pragma unroll
  for (int i = 0; i < 8; ++i)
    reinterpret_cast<float4*>(s)[tid + i * 256] =
        reinterpret_cast<const float4*>(row)[tid + i * 256];
  for (int h = 1; h < 8192; h <<= 1) {
    __syncthreads();
#pragma unroll
    for (int it = 0; it < 16; ++it) {
      int i = tid + it * 256;
      int j = ((i & ~(h - 1)) << 1) | (i & (h - 1));
      float a = s[j], b = s[j + h];
      s[j] = a + b;
      s[j + h] = a - b;
    }
  }
  __syncthreads();
  const float scale = 0.011048543456039806f;  // 1/sqrt(8192)
  unsigned short* orow = out + (size_t)blockIdx.x * 8192;
#pragma unroll
  for (int i = 0; i < 8; ++i) {
    float4 v = reinterpret_cast<const float4*>(s)[tid + i * 256];
    ushort4 o;
    o.x = f32_to_bf16(v.x * scale);
    o.y = f32_to_bf16(v.y * scale);
    o.z = f32_to_bf16(v.z * scale);
    o.w = f32_to_bf16(v.w * scale);
    reinterpret_cast<ushort4*>(orow)[tid + i * 256] = o;
  }
}

// ======================= GEMM2: C(f32) = A · Bt^T ==========================
// tile 256x256, BK=64, 8 waves (2M x 4N), per-wave 128x64.
// Best-measured structure (R6): stage all 8 gloads at tile head, coarse
// counted-lgkm gates, 1 barrier + 1 vmcnt(0) per K-tile (drain is free:
// gloads issued ~5000 cyc earlier).
#define G2_TILE(bi, tt)                                                       \
  {                                                                           \
    if ((tt) + 1 < NT) {                                                      \
      unsigned short* dA = L + (((bi) ^ 1) * 16384) + wid * 512;              \
      unsigned short* dB = L + 32768 + (((bi) ^ 1) * 16384) + wid * 512;      \
      _Pragma("unroll") for (int i = 0; i < 4; ++i) {                         \
        GLOAD_LDS16(pA + i * s64, dA + i * 4096);                             \
        GLOAD_LDS16(pB + i * s64, dB + i * 4096);                             \
      }                                                                       \
    }                                                                         \
    SB0();                                                                    \
    _Pragma("unroll") for (int m = 0; m < 4; ++m) {                           \
      ra[m][0] = *(const bf16x8*)(Lb + ((bi)*32768 + m * 2048) + rA0);        \
      ra[m][1] = *(const bf16x8*)(Lb + ((bi)*32768 + m * 2048) + rA1);        \
    }                                                                         \
    _Pragma("unroll") for (int n = 0; n < 2; ++n) {                           \
      rb[n][0] = *(const bf16x8*)(Lb + ((bi)*32768 + n * 2048) + rB0);        \
      rb[n][1] = *(const bf16x8*)(Lb + ((bi)*32768 + n * 2048) + rB1);        \
    }                                                                         \
    SB0();                                                                    \
    _Pragma("unroll") for (int n = 2; n < 4; ++n) {                           \
      rb[n][0] = *(const bf16x8*)(Lb + ((bi)*32768 + n * 2048) + rB0);        \
      rb[n][1] = *(const bf16x8*)(Lb + ((bi)*32768 + n * 2048) + rB1);        \
    }                                                                         \
    SB0();                                                                    \
    LGKM(4);                                                                  \
    PRIO1();                                                                  \
    _Pragma("unroll") for (int m = 0; m < 4; ++m)                             \
        _Pragma("unroll") for (int n = 0; n < 2; ++n) {                       \
      acc[m][n] = MFMA_BF16(ra[m][0], rb[n][0], acc[m][n], 0, 0, 0);          \
      acc[m][n] = MFMA_BF16(ra[m][1], rb[n][1], acc[m][n], 0, 0, 0);          \
    }                                                                         \
    PRIO0();                                                                  \
    SB0();                                                                    \
    LGKM(0);                                                                  \
    PRIO1();                                                                  \
    _Pragma("unroll") for (int m = 0; m < 4; ++m)                             \
        _Pragma("unroll") for (int n = 2; n < 4; ++n) {                       \
      acc[m][n] = MFMA_BF16(ra[m][0], rb[n][0], acc[m][n], 0, 0, 0);          \
      acc[m][n] = MFMA_BF16(ra[m][1], rb[n][1], acc[m][n], 0, 0, 0);          \
    }                                                                         \
    PRIO0();                                                                  \
    SB0();                                                                    \
    _Pragma("unroll") for (int m = 0; m < 4; ++m) {                           \
      ra[m][0] = *(const bf16x8*)(Lb + ((bi)*32768 + (m + 4) * 2048) + rA0);  \
      ra[m][1] = *(const bf16x8*)(Lb + ((bi)*32768 + (m + 4) * 2048) + rA1);  \
    }                                                                         \
    SB0();                                                                    \
    LGKM(0);                                                                  \
    PRIO1();                                                                  \
    _Pragma("unroll") for (int m = 0; m < 4; ++m)                             \
        _Pragma("unroll") for (int n = 2; n < 4; ++n) {                       \
      acc[4 + m][n] = MFMA_BF16(ra[m][0], rb[n][0], acc[4 + m][n], 0, 0, 0);  \
      acc[4 + m][n] = MFMA_BF16(ra[m][1], rb[n][1], acc[4 + m][n], 0, 0, 0);  \
    }                                                                         \
    _Pragma("unroll") for (int m = 0; m < 4; ++m)                             \
        _Pragma("unroll") for (int n = 0; n < 2; ++n) {                       \
      acc[4 + m][n] = MFMA_BF16(ra[m][0], rb[n][0], acc[4 + m][n], 0, 0, 0);  \
      acc[4 + m][n] = MFMA_BF16(ra[m][1], rb[n][1], acc[4 + m][n], 0, 0, 0);  \
    }                                                                         \
    PRIO0();                                                                  \
    VMCNT0();                                                                 \
    BAR();                                                                    \
    pA += 128;                                                                \
    pB += 128;                                                                \
  }

__launch_bounds__(512, 2)
__global__ void gemm2_pipe(const unsigned short* __restrict__ A,
                           const unsigned short* __restrict__ Bt,
                           float* __restrict__ C, int M, int N, int K) {
  __shared__ __align__(16) unsigned short L[65536];  // A:[0,64KB) B:[64,128KB)
  const int tid = threadIdx.x, lane = tid & 63, wid = tid >> 6;
  const int wr = wid >> 2, wc = wid & 3;
  const int nbx = N >> 8;
  const int cpx = (int)gridDim.x >> 3;
  const int swz = ((int)blockIdx.x & 7) * cpx + ((int)blockIdx.x >> 3);
  const int bm = (swz / nbx) << 8, bn = (swz % nbx) << 8;
  const int NT = K >> 6;

  const int lp0 = (lane & 15) * 128 + (((lane >> 4) << 4) ^ ((lane & 7) << 4));
  const int lp1 =
      (lane & 15) * 128 + ((64 | ((lane >> 4) << 4)) ^ ((lane & 7) << 4));
  const int rA0 = wr * 16384 + lp0, rA1 = wr * 16384 + lp1;
  const int rB0 = 65536 + wc * 8192 + lp0, rB1 = 65536 + wc * 8192 + lp1;

  const int swzc = ((lane & 7) ^ (lane >> 3)) << 4;
  const char* pA = (const char*)A +
                   ((size_t)(bm + (wid << 3) + (lane >> 3)) * K) * 2 + swzc;
  const char* pB = (const char*)Bt +
                   ((size_t)(bn + (wid << 3) + (lane >> 3)) * K) * 2 + swzc;
  const size_t s64 = (size_t)K * 128;
  const char* Lb = (const char*)L;

  {  // prologue: stage tile 0 into buf0
    unsigned short* dA = L + wid * 512;
    unsigned short* dB = L + 32768 + wid * 512;
#pragma unroll
    for (int i = 0; i < 4; ++i) {
      GLOAD_LDS16(pA + i * s64, dA + i * 4096);
      GLOAD_LDS16(pB + i * s64, dB + i * 4096);
    }
  }
  pA += 128;
  pB += 128;

  f32x4 acc[8][4];
#pragma unroll
  for (int m = 0; m < 8; ++m)
#pragma unroll
    for (int n = 0; n < 4; ++n) acc[m][n] = (f32x4)0.0f;
  bf16x8 ra[4][2], rb[4][2];

  VMCNT0();
  BAR();

  for (int t = 0; t < NT; t += 2) {
    G2_TILE(0, t)
    G2_TILE(1, t + 1)
  }

  const int er = (lane >> 4) << 2;
  const int ec = lane & 15;
#pragma unroll
  for (int mi = 0; mi < 8; ++mi)
#pragma unroll
    for (int n = 0; n < 4; ++n)
#pragma unroll
      for (int r = 0; r < 4; ++r) {
        size_t row = (size_t)(bm + wr * 128 + mi * 16 + er + r);
        size_t col = (size_t)(bn + wc * 64 + n * 16 + ec);
        C[row * N + col] = acc[mi][n][r];
      }
}

// ======================= GEMM1: dual-B + silu fuse =========================
// tile 256x128, BK=64, 8 waves (4M x 2N), per-wave 64x64, dual accum.
// LDS (ushorts): A [0,32768), B1 [32768,49152), B3 [49152,65536).
// Stage at tile head; 1 barrier + 1 vmcnt(0) per K-tile.
#define G1_TILE(bi, tt)                                                       \
  {                                                                           \
    if ((tt) + 1 < NT) {                                                      \
      unsigned short* dA = L + (((bi) ^ 1) * 16384) + wid * 512;              \
      unsigned short* dB1 = L + 32768 + (((bi) ^ 1) * 8192) + wid * 512;      \
      unsigned short* dB3 = L + 49152 + (((bi) ^ 1) * 8192) + wid * 512;      \
      _Pragma("unroll") for (int i = 0; i < 4; ++i)                           \
          GLOAD_LDS16(pA + i * s64, dA + i * 4096);                           \
      _Pragma("unroll") for (int i = 0; i < 2; ++i) {                         \
        GLOAD_LDS16(pB1 + i * s64, dB1 + i * 4096);                           \
        GLOAD_LDS16(pB3 + i * s64, dB3 + i * 4096);                           \
      }                                                                       \
    }                                                                         \
    SB0();                                                                    \
    _Pragma("unroll") for (int m = 0; m < 4; ++m) {                           \
      ra[m][0] = *(const bf16x8*)(Lb + ((bi)*32768 + m * 2048) + rA0);        \
      ra[m][1] = *(const bf16x8*)(Lb + ((bi)*32768 + m * 2048) + rA1);        \
    }                                                                         \
    _Pragma("unroll") for (int n = 0; n < 2; ++n) {                           \
      rb[n][0] = *(const bf16x8*)(Lb + ((bi)*16384 + n * 2048) + rB0);        \
      rb[n][1] = *(const bf16x8*)(Lb + ((bi)*16384 + n * 2048) + rB1);        \
    }                                                                         \
    SB0();                                                                    \
    _Pragma("unroll") for (int n = 2; n < 4; ++n) {                           \
      rb[n][0] = *(const bf16x8*)(Lb + ((bi)*16384 + n * 2048) + rB0);        \
      rb[n][1] = *(const bf16x8*)(Lb + ((bi)*16384 + n * 2048) + rB1);        \
    }                                                                         \
    SB0();                                                                    \
    LGKM(4);                                                                  \
    PRIO1();                                                                  \
    _Pragma("unroll") for (int m = 0; m < 4; ++m)                             \
        _Pragma("unroll") for (int n = 0; n < 2; ++n) {                       \
      accG[m][n] = MFMA_BF16(ra[m][0], rb[n][0], accG[m][n], 0, 0, 0);        \
      accG[m][n] = MFMA_BF16(ra[m][1], rb[n][1], accG[m][n], 0, 0, 0);        \
    }                                                                         \
    PRIO0();                                                                  \
    SB0();                                                                    \
    LGKM(0);                                                                  \
    PRIO1();                                                                  \
    _Pragma("unroll") for (int m = 0; m < 4; ++m)                             \
        _Pragma("unroll") for (int n = 2; n < 4; ++n) {                       \
      accG[m][n] = MFMA_BF16(ra[m][0], rb[n][0], accG[m][n], 0, 0, 0);        \
      accG[m][n] = MFMA_BF16(ra[m][1], rb[n][1], accG[m][n], 0, 0, 0);        \
    }                                                                         \
    PRIO0();                                                                  \
    SB0();                                                                    \
    _Pragma("unroll") for (int n = 2; n < 4; ++n) { /* B3 n2,3 first */       \
      rb[n][0] = *(const bf16x8*)(Lb + (32768 + (bi)*16384 + n * 2048) + rB0);\
      rb[n][1] = *(const bf16x8*)(Lb + (32768 + (bi)*16384 + n * 2048) + rB1);\
    }                                                                         \
    SB0();                                                                    \
    _Pragma("unroll") for (int n = 0; n < 2; ++n) {                           \
      rb[n][0] = *(const bf16x8*)(Lb + (32768 + (bi)*16384 + n * 2048) + rB0);\
      rb[n][1] = *(const bf16x8*)(Lb + (32768 + (bi)*16384 + n * 2048) + rB1);\
    }                                                                         \
    SB0();                                                                    \
    LGKM(4);                                                                  \
    PRIO1();                                                                  \
    _Pragma("unroll") for (int m = 0; m < 4; ++m)                             \
        _Pragma("unroll") for (int n = 2; n < 4; ++n) {                       \
      accL[m][n] = MFMA_BF16(ra[m][0], rb[n][0], accL[m][n], 0, 0, 0);        \
      accL[m][n] = MFMA_BF16(ra[m][1], rb[n][1], accL[m][n], 0, 0, 0);        \
    }                                                                         \
    PRIO0();                                                                  \
    SB0();                                                                    \
    LGKM(0);                                                                  \
    PRIO1();                                                                  \
    _Pragma("unroll") for (int m = 0; m < 4; ++m)                             \
        _Pragma("unroll") for (int n = 0; n < 2; ++n) {                       \
      accL[m][n] = MFMA_BF16(ra[m][0], rb[n][0], accL[m][n], 0, 0, 0);        \
      accL[m][n] = MFMA_BF16(ra[m][1], rb[n][1], accL[m][n], 0, 0, 0);        \
    }                                                                         \
    PRIO0();                                                                  \
    VMCNT0();                                                                 \
    BAR();                                                                    \
    pA += 128;                                                                \
    pB1 += 128;                                                               \
    pB3 += 128;                                                               \
  }

__launch_bounds__(512, 2)
__global__ void gemm1_pipe(const unsigned short* __restrict__ A,
                           const unsigned short* __restrict__ B1p,
                           const unsigned short* __restrict__ B3p,
                           unsigned short* __restrict__ Hout, int M, int N,
                           int K) {
  __shared__ __align__(16) unsigned short L[65536];
  const int tid = threadIdx.x, lane = tid & 63, wid = tid >> 6;
  const int wr = wid >> 1, wc = wid & 1;
  const int nby = M >> 8;  // 32
  const int cpx = (int)gridDim.x >> 3;
  const int swz = ((int)blockIdx.x & 7) * cpx + ((int)blockIdx.x >> 3);
  const int bm = (swz % nby) << 8;
  const int bn = (swz / nby) << 7;
  const int NT = K >> 6;

  const int lp0 = (lane & 15) * 128 + (((lane >> 4) << 4) ^ ((lane & 7) << 4));
  const int lp1 =
      (lane & 15) * 128 + ((64 | ((lane >> 4) << 4)) ^ ((lane & 7) << 4));
  const int rA0 = wr * 8192 + lp0, rA1 = wr * 8192 + lp1;
  const int rB0 = 65536 + wc * 8192 + lp0, rB1 = 65536 + wc * 8192 + lp1;

  const int swzc = ((lane & 7) ^ (lane >> 3)) << 4;
  const char* pA = (const char*)A +
                   ((size_t)(bm + (wid << 3) + (lane >> 3)) * K) * 2 + swzc;
  const char* pB1 = (const char*)B1p +
                    ((size_t)(bn + (wid << 3) + (lane >> 3)) * K) * 2 + swzc;
  const char* pB3 = (const char*)B3p +
                    ((size_t)(bn + (wid << 3) + (lane >> 3)) * K) * 2 + swzc;
  const size_t s64 = (size_t)K * 128;
  const char* Lb = (const char*)L;

  {  // prologue
    unsigned short* dA = L + wid * 512;
    unsigned short* dB1 = L + 32768 + wid * 512;
    unsigned short* dB3 = L + 49152 + wid * 512;
#pragma unroll
    for (int i = 0; i < 4; ++i) GLOAD_LDS16(pA + i * s64, dA + i * 4096);
#pragma unroll
    for (int i = 0; i < 2; ++i) {
      GLOAD_LDS16(pB1 + i * s64, dB1 + i * 4096);
      GLOAD_LDS16(pB3 + i * s64, dB3 + i * 4096);
    }
  }
  pA += 128;
  pB1 += 128;
  pB3 += 128;

  f32x4 accG[4][4], accL[4][4];
#pragma unroll
  for (int m = 0; m < 4; ++m)
#pragma unroll
    for (int n = 0; n < 4; ++n) {
      accG[m][n] = (f32x4)0.0f;
      accL[m][n] = (f32x4)0.0f;
    }
  bf16x8 ra[4][2], rb[4][2];

  VMCNT0();
  BAR();

  for (int t = 0; t < NT; t += 2) {
    G1_TILE(0, t)
    G1_TILE(1, t + 1)
  }

  const int er = (lane >> 4) << 2;
  const int ec = lane & 15;
#pragma unroll
  for (int m = 0; m < 4; ++m)
#pragma unroll
    for (int n = 0; n < 4; ++n)
#pragma unroll
      for (int r = 0; r < 4; ++r) {
        float g = accG[m][n][r];
        float li = accL[m][n][r];
        float h = (g / (1.0f + __expf(-g))) * li;
        size_t row = (size_t)(bm + wr * 64 + m * 16 + er + r);
        size_t col = (size_t)(bn + wc * 64 + n * 16 + ec);
        Hout[row * N + col] = f32_to_bf16(h);
      }
}

extern "C" void kernel_launch(void* const* d_in, const int* in_sizes, int n_in,
                              void* d_out, int out_size, void* d_ws,
                              size_t ws_size, hipStream_t stream) {
  const float* x = (const float*)d_in[0];   // (4,2048,2048)
  const float* W1 = (const float*)d_in[1];  // (8192,2048)
  const float* W2 = (const float*)d_in[2];  // (2048,8192)
  const float* W3 = (const float*)d_in[3];  // (8192,2048)
  float* out = (float*)d_out;

  const int M = 8192, D = 2048, H = 8192;
  const size_t NE = (size_t)16777216;

  unsigned short* xb = (unsigned short*)d_ws;
  unsigned short* w1b = xb + NE;
  unsigned short* w3b = w1b + NE;
  unsigned short* w2f = w3b + NE;
  unsigned short* hid = w2f + NE;  // M x H bf16

  conv3_f32_bf16<<<3072, 256, 0, stream>>>(x, xb, W1, w1b, W3, w3b,
                                           (int)(NE / 4));
  fwht_rows_bf16<<<2048, 256, 0, stream>>>(W2, w2f);

  gemm1_pipe<<<(M / 256) * (H / 128), 512, 0, stream>>>(xb, w1b, w3b, hid, M,
                                                        H, D);
  gemm2_pipe<<<(M / 256) * (D / 256), 512, 0, stream>>>(hid, w2f, out, M, D,
                                                        H);
}